// Round 2
// baseline (132.691 us; speedup 1.0000x reference)
//
#include <hip/hip_runtime.h>
#include <hip/hip_bf16.h>

#define BATCH 32
#define SEQ 4096
#define DMODEL 256
#define NCLS 5

typedef short          s8v  __attribute__((ext_vector_type(8)));  // 8 bf16 frag
typedef unsigned short u4v  __attribute__((ext_vector_type(4)));
typedef float          f4v  __attribute__((ext_vector_type(4)));  // C/D frag

// RNE fp32->bf16 via compiler path (fuses to v_cvt_pk_bf16_f32, m240)
__device__ __forceinline__ unsigned short f2bs(float f) {
    __hip_bfloat16 h = __float2bfloat16(f);
    return *reinterpret_cast<unsigned short*>(&h);
}
// DPP row_shr within 16-lane rows, 0-fill (bound_ctrl) -- rows align with m16
__device__ __forceinline__ float dpp_shr4(float v) {
    return __int_as_float(__builtin_amdgcn_update_dpp(
        0, __float_as_int(v), 0x114, 0xF, 0xF, true));
}
__device__ __forceinline__ float dpp_shr8(float v) {
    return __int_as_float(__builtin_amdgcn_update_dpp(
        0, __float_as_int(v), 0x118, 0xF, 0xF, true));
}
// ds_swizzle BitMode: lane -> lane|12 (broadcast chunk-3 lane of each 16-row)
__device__ __forceinline__ float swz_or12(float v) {
    return __int_as_float(__builtin_amdgcn_ds_swizzle(
        __float_as_int(v), 0x019F));
}

// Grid 512 = 256 d x 2 batch-halves; block = 8 waves, 2 blocks/CU (LDS 63KB),
// 16 waves/CU = 4/SIMD (vs 2 before). Wave PAIR (pair=wid>>1) owns 16 cols
// (4 batches x 4 chunks, col m16 -> b=bh*16+pair*4+(m16&3), chunk=m16>>2);
// within the pair, half nh=wid&1 owns states n in [nh*32,nh*32+32) for the
// B-phase/scan and output rows t in [nh*32,+32) for the D-phase. Halves
// exchange Sig/Xb via LDS with 2 __syncthreads per group; with 2 blocks/CU
// the barrier drain overlaps across blocks.
// Per group (256 timesteps):
//   B: vB[n,col] = MA'[n,j]*Xb[j,col] + cq   (MA'[n][j]=Pn*A^{63-j}, C-in=cq)
//   scan: 4-chunk prefix in-wave via DPP row_shr4/8 + or12 broadcast;
//      sigma0' = A^256*sigma0 + bcast(incl@c=3); Sig snapshot = e + a^c*sigma0
//   D: y = CAT x Sig + TG x Xb (C-in = Hcp; Dw*x folded into TG diagonal)
//      -> gelu -> per-lane pool; head fused via atomicAdd at the end.
// MFMA 16x16x32 bf16 layouts (verified m89/m91): A[m=lane&15][k=quad*8+j],
// B[k=quad*8+j][n=lane&15], D: col=lane&15, row=quad*4+reg.
__global__ __launch_bounds__(512, 4) void ssm_mfma_kernel(
    const float* __restrict__ x,      // [B, T]
    const float* __restrict__ w_in,   // [D]
    const float* __restrict__ b_in,   // [D]
    const float* __restrict__ A_diag, // [D, 64]
    const float* __restrict__ B_in,   // [D, 64]
    const float* __restrict__ C_out,  // [D, 64]
    const float* __restrict__ D_skip, // [D]
    const float* __restrict__ W_head, // [2D, NCLS]
    const float* __restrict__ b_head, // [NCLS]
    float* __restrict__ out)          // [B, NCLS] (pre-zeroed, atomic accum)
{
    __shared__ float          Pow [65 * 64];   // Pow[m*64+n] = A_n^m
    __shared__ unsigned short MAb [64 * 72];
    __shared__ unsigned short CATb[64 * 72];
    __shared__ unsigned short TGb [64 * 72];
    __shared__ unsigned short Xb  [64 * 72];   // 64 cols (16 b x 4 chunks)
    __shared__ unsigned short Sigb[64 * 72];
    __shared__ float Pf[64], Qf[64], Gf[64], Hf[64], HcpS[64], Anf[64], cqS[64];
    __shared__ float psA[16], pmA[16], psB[16], pmB[16];

    const int tid  = threadIdx.x;
    const int lane = tid & 63;
    const int wid  = tid >> 6;
    const int m16  = lane & 15;
    const int q    = lane >> 4;
    const int q4   = q * 4;
    const int q8   = q * 8;
    const int d    = blockIdx.x >> 1;
    const int bh   = blockIdx.x & 1;

    const int pair = wid >> 1;       // 0..3: col group
    const int nh   = wid & 1;        // 0..1: n-half / t-half
    const int nb   = nh * 32;        // state base for B/scan
    const int tb   = nh * 32;        // output-row base for D
    const int pcol = pair * 16 + m16;

    const float wd = w_in[d], bd = b_in[d];
    const float Dw = D_skip[d] * wd;
    const float Db = D_skip[d] * bd;

    // staging geometry: thread stages col cg (8 floats per group)
    const int cg    = tid >> 3;               // 0..63
    const int j0    = (tid & 7) * 8;
    const int bglob = bh * 16 + (cg >> 4) * 4 + (cg & 3);
    const int cch   = (cg & 15) >> 2;
    const float* xrow = x + bglob * SEQ + cch * 64 + j0;
    unsigned short* xdst = &Xb[cg * 72 + j0];

    // issue group-0 loads immediately; setup hides the latency
    float4 xl0 = ((const float4*)xrow)[0];
    float4 xl1 = ((const float4*)xrow)[1];

    // ---- setup 1: per-n tables + power table (wave 0) ----
    if (tid < 64) {
        const int n = tid;
        const float An = A_diag[d * 64 + n];
        const float CB = B_in[d * 64 + n] * C_out[d * 64 + n];
        Anf[n] = An; Pf[n] = CB * wd; Qf[n] = CB * bd;
        float p = 1.0f;
        for (int m = 0; m <= 64; ++m) { Pow[m * 64 + n] = p; p *= An; }
    }
    __syncthreads();
    // ---- setup 2: G/H = Pow x {P,Q} matvec, 8 threads per row ----
    {
        const int mrow = tid >> 3, p8 = (tid & 7) * 8;
        float g = 0.0f, h = 0.0f;
        #pragma unroll
        for (int jj = 0; jj < 8; ++jj) {
            const float pw = Pow[mrow * 64 + p8 + jj];
            g = fmaf(pw, Pf[p8 + jj], g);
            h = fmaf(pw, Qf[p8 + jj], h);
        }
        g += __shfl_xor(g, 1, 64); g += __shfl_xor(g, 2, 64); g += __shfl_xor(g, 4, 64);
        h += __shfl_xor(h, 1, 64); h += __shfl_xor(h, 2, 64); h += __shfl_xor(h, 4, 64);
        if ((tid & 7) == 0) { Gf[mrow] = g; Hf[mrow] = h; }
    }
    __syncthreads();
    // ---- setup 3: MA'/CAT/TG matrices + Hcp prefix + cq ----
    {
        const int r0 = tid >> 3, c0 = (tid & 7) * 8;
        #pragma unroll
        for (int jj = 0; jj < 8; ++jj) {
            const int j = c0 + jj;
            MAb [r0 * 72 + j] = f2bs(Pf[r0] * Pow[(63 - j) * 64 + r0]);
            CATb[r0 * 72 + j] = f2bs(Pow[(r0 + 1) * 64 + j]);
            TGb [r0 * 72 + j] = (j < r0)  ? f2bs(Gf[r0 - j])
                              : (j == r0) ? f2bs(Gf[0] + Dw)   // Dw*x folded in
                                          : (unsigned short)0;
        }
        if (tid < 64) {
            float v = Hf[tid];
            #pragma unroll
            for (int dl = 1; dl < 64; dl <<= 1) {
                const float t = __shfl(v, (tid - dl) & 63, 64);
                v += (tid >= dl) ? t : 0.0f;
            }
            HcpS[tid] = v + Db;
            const float A64 = Pow[64 * 64 + tid];
            cqS[tid] = Qf[tid] * (1.0f - A64) / (1.0f - Anf[tid]);
        }
    }
    __syncthreads();

    // ---- loop-invariant registers: half-sized fragment set (48 VGPR) ----
    s8v aMA[2][2], aCAT[2][2], aTG[2][2];
    #pragma unroll
    for (int rt = 0; rt < 2; ++rt)
        #pragma unroll
        for (int kb = 0; kb < 2; ++kb) {
            aMA [rt][kb] = *(const s8v*)&MAb [(nb + rt * 16 + m16) * 72 + kb * 32 + q8];
            aCAT[rt][kb] = *(const s8v*)&CATb[(tb + rt * 16 + m16) * 72 + kb * 32 + q8];
            aTG [rt][kb] = *(const s8v*)&TGb [(tb + rt * 16 + m16) * 72 + kb * 32 + q8];
        }
    float a64v[2][4], acv[2][4], sig0[2][4];
    const int cc = m16 >> 2;                   // this col's chunk index
    #pragma unroll
    for (int rt = 0; rt < 2; ++rt)
        #pragma unroll
        for (int r = 0; r < 4; ++r) {
            const int nn = nb + rt * 16 + q4 + r;
            const float a = Pow[64 * 64 + nn];           // A^64
            a64v[rt][r] = a;
            const float a2 = a * a;
            acv [rt][r] = ((cc & 1) ? a : 1.0f) * ((cc & 2) ? a2 : 1.0f);  // a^c
            sig0[rt][r] = 0.0f;
        }

    // ---- prologue: stage group 0 ----
    {
        uint4 w;
        w.x = (unsigned)f2bs(xl0.x) | ((unsigned)f2bs(xl0.y) << 16);
        w.y = (unsigned)f2bs(xl0.z) | ((unsigned)f2bs(xl0.w) << 16);
        w.z = (unsigned)f2bs(xl1.x) | ((unsigned)f2bs(xl1.y) << 16);
        w.w = (unsigned)f2bs(xl1.z) | ((unsigned)f2bs(xl1.w) << 16);
        *(uint4*)xdst = w;
    }
    __syncthreads();

    float psum = 0.0f, pmax = -1e30f;

    #pragma unroll 1
    for (int g = 0; g < 16; ++g) {
        // issue-early loads for group g+1 (drain covered by B+scan phase)
        float4 yl0, yl1;
        if (g < 15) {
            const float4* xg = (const float4*)(xrow + (g + 1) * 256);
            yl0 = xg[0]; yl1 = xg[1];
        }
        // ---- B: vB = cq + MA' x Xb (own n-half) ----
        const s8v bx0 = *(const s8v*)&Xb[pcol * 72 + q8];
        const s8v bx1 = *(const s8v*)&Xb[pcol * 72 + 32 + q8];
        f4v vB[2];
        #pragma unroll
        for (int rt = 0; rt < 2; ++rt) {
            const f4v cqv = *(const f4v*)&cqS[nb + rt * 16 + q4];
            vB[rt] = __builtin_amdgcn_mfma_f32_16x16x32_bf16(aMA[rt][0], bx0, cqv, 0, 0, 0);
            vB[rt] = __builtin_amdgcn_mfma_f32_16x16x32_bf16(aMA[rt][1], bx1, vB[rt], 0, 0, 0);
        }
        // ---- in-wave 4-chunk scan (DPP) + Sig snapshot (own n-half) ----
        #pragma unroll
        for (int rt = 0; rt < 2; ++rt) {
            u4v sg;
            #pragma unroll
            for (int r = 0; r < 4; ++r) {
                const float a  = a64v[rt][r];
                const float v  = vB[rt][r];
                const float t1 = dpp_shr4(v);            // v@(c-1), 0 at c=0
                const float i1 = fmaf(a, t1, v);
                const float t2 = dpp_shr8(i1);           // 0 at c<2
                const float e  = fmaf(a, t2, t1);        // exact exclusive prefix
                const float se = fmaf(acv[rt][r], sig0[rt][r], e);
                const float i2 = fmaf(a, e, v);          // inclusive prefix
                const float S  = swz_or12(i2);           // broadcast c=3 lane
                const float a2 = a * a;
                sig0[rt][r] = fmaf(a2 * a2, sig0[rt][r], S);   // A^256 advance
                sg[r] = f2bs(se);
            }
            *(u4v*)&Sigb[pcol * 72 + nb + rt * 16 + q4] = sg;
        }
        __syncthreads();   // #1: Sigb (both halves) ready; Xb reads done

        // ---- stage Xb for g+1 (Xb free after #1; visible after #2) ----
        const s8v bs0 = *(const s8v*)&Sigb[pcol * 72 + q8];
        const s8v bs1 = *(const s8v*)&Sigb[pcol * 72 + 32 + q8];
        if (g < 15) {
            uint4 w;
            w.x = (unsigned)f2bs(yl0.x) | ((unsigned)f2bs(yl0.y) << 16);
            w.y = (unsigned)f2bs(yl0.z) | ((unsigned)f2bs(yl0.w) << 16);
            w.z = (unsigned)f2bs(yl1.x) | ((unsigned)f2bs(yl1.y) << 16);
            w.w = (unsigned)f2bs(yl1.z) | ((unsigned)f2bs(yl1.w) << 16);
            *(uint4*)xdst = w;
        }
        // ---- D: y = Hcp + CAT x Sig + TG x Xb (own t-half) -> gelu -> pool
        #pragma unroll
        for (int rt = 0; rt < 2; ++rt) {
            const f4v hcpv = *(const f4v*)&HcpS[tb + rt * 16 + q4];
            f4v acc = __builtin_amdgcn_mfma_f32_16x16x32_bf16(aCAT[rt][0], bs0, hcpv, 0, 0, 0);
            acc = __builtin_amdgcn_mfma_f32_16x16x32_bf16(aCAT[rt][1], bs1, acc, 0, 0, 0);
            acc = __builtin_amdgcn_mfma_f32_16x16x32_bf16(aTG [rt][0], bx0, acc, 0, 0, 0);
            acc = __builtin_amdgcn_mfma_f32_16x16x32_bf16(aTG [rt][1], bx1, acc, 0, 0, 0);
            #pragma unroll
            for (int r = 0; r < 4; ++r) {
                const float yt = acc[r];
                const float y2 = yt * yt;
                const float zn = yt * fmaf(-0.07135481627f, y2, -1.5957691216f);
                const float h  = yt * __builtin_amdgcn_rcpf(1.0f + __expf(zn));
                psum += h;
                pmax = fmaxf(pmax, h);
            }
        }
        __syncthreads();   // #2: Sigb reads done; Xb(g+1) visible
    }

    // ---- pool: reduce lanes sharing b_loc = lane&3, combine halves in LDS
    #pragma unroll
    for (int dl = 4; dl <= 32; dl <<= 1) {
        psum += __shfl_xor(psum, dl, 64);
        pmax  = fmaxf(pmax, __shfl_xor(pmax, dl, 64));
    }
    if (lane < 4) {
        const int idx = pair * 4 + lane;
        if (nh == 0) { psA[idx] = psum; pmA[idx] = pmax; }
        else         { psB[idx] = psum; pmB[idx] = pmax; }
    }
    __syncthreads();
    // ---- fused head: out[b,c] += avg*W[d,c] + max*W[D+d,c] (+bias once) ----
    if (tid < 16) {
        const int bg = bh * 16 + tid;
        const float s  = (psA[tid] + psB[tid]) * (1.0f / SEQ);
        const float mx = fmaxf(pmA[tid], pmB[tid]);
        #pragma unroll
        for (int c = 0; c < NCLS; ++c) {
            float contrib = s  * W_head[d * NCLS + c]
                          + mx * W_head[(DMODEL + d) * NCLS + c];
            if (d == 0) contrib += b_head[c];   // each (b,c) gets bias once
            atomicAdd(&out[bg * NCLS + c], contrib);
        }
    }
}

extern "C" void kernel_launch(void* const* d_in, const int* in_sizes, int n_in,
                              void* d_out, int out_size, void* d_ws, size_t ws_size,
                              hipStream_t stream) {
    const float* x      = (const float*)d_in[0];
    const float* w_in   = (const float*)d_in[1];
    const float* b_in   = (const float*)d_in[2];
    const float* A_diag = (const float*)d_in[3];
    const float* B_in   = (const float*)d_in[4];
    const float* C_out  = (const float*)d_in[5];
    const float* D_skip = (const float*)d_in[6];
    const float* W_head = (const float*)d_in[7];
    const float* b_head = (const float*)d_in[8];
    float* out = (float*)d_out;

    hipMemsetAsync(out, 0, BATCH * NCLS * sizeof(float), stream);
    ssm_mfma_kernel<<<DMODEL * 2, 512, 0, stream>>>(x, w_in, b_in, A_diag, B_in,
                                                    C_out, D_skip, W_head, b_head, out);
}